// Round 12
// baseline (300.058 us; speedup 1.0000x reference)
//
#include <hip/hip_runtime.h>

typedef __attribute__((ext_vector_type(4))) float f32x4;
typedef __attribute__((ext_vector_type(8))) __bf16 bf16x8;

constexpr int FD = 128;   // feature dim D = H = 128

__device__ __forceinline__ uint4 pack8(const float* v) {
  union { __bf16 h[8]; uint4 u; } cv;
#pragma unroll
  for (int q = 0; q < 8; ++q) cv.h[q] = (__bf16)v[q];
  return cv.u;
}
__device__ __forceinline__ uint4 pack8v(const f32x4 a, const f32x4 b) {
  float v[8];
#pragma unroll
  for (int q = 0; q < 4; ++q) { v[q] = a[q]; v[4 + q] = b[q]; }
  return pack8(v);
}

// node_x f32 -> bf16 table (halves random-gather bytes in the edge kernel)
__global__ void cvt_bf16(const float* __restrict__ x, unsigned short* __restrict__ o, int n8) {
  int i = blockIdx.x * 256 + threadIdx.x;
  if (i >= n8) return;
  const float* p = x + (size_t)i * 8;
  float v[8];
#pragma unroll
  for (int q = 0; q < 8; ++q) v[q] = p[q];
  *(uint4*)(o + (size_t)i * 8) = pack8(v);
}

// Pack a (K,128) f32 weight matrix into 16x16x32 MFMA B-fragment order, bf16:
// dst[((nt*KS + ks)*64 + lane)*8 + e] = W[k][n]
__global__ void pack_weights(const float* __restrict__ mw0, const float* __restrict__ mw1,
                             const float* __restrict__ mw2, const float* __restrict__ uw0,
                             const float* __restrict__ uw1, const float* __restrict__ uw2,
                             unsigned short* __restrict__ wp) {
  int tid = blockIdx.x * 256 + threadIdx.x;   // 576*256 == 147456 exactly
  const float* src; int base, K;
  if      (tid < 49152)  { src = mw0; base = 0;      K = 384; }
  else if (tid < 65536)  { src = mw1; base = 49152;  K = 128; }
  else if (tid < 81920)  { src = mw2; base = 65536;  K = 128; }
  else if (tid < 114688) { src = uw0; base = 81920;  K = 256; }
  else if (tid < 131072) { src = uw1; base = 114688; K = 128; }
  else                   { src = uw2; base = 131072; K = 128; }
  int i = tid - base;
  int k = i >> 7, n = i & 127;
  int KS = K >> 5;
  int dst = base + (((n >> 4) * KS + (k >> 5)) * 64 + ((k >> 3) & 3) * 16 + (n & 15)) * 8 + (k & 7);
  union { __bf16 h; unsigned short s; } cv; cv.h = (__bf16)src[i];
  wp[dst] = cv.s;
}

// Frag-order LDS layout with grp-keyed XOR sub-chunk permutation:
// data (row, jc) [jc = 16B col-chunk 0..7 per 128-col tile region] lives at
//   grp = (jc>>2)*4 + (row>>4),  q = ((row&15)*4 + (jc&3)) ^ ((grp>>2)&3)
//   short addr = tileBase + grp*512 + q*8 (+ within-chunk)
// MFMA reads (grp = ks*4+m, q = (ln*4+g16)^(ks&3)) stay conflict-free; wide
// staging writes become minimal (4 sub-chunks permuted by the XOR key).

// Edge kernel: 64 edges/block, 512 threads = 8 waves, wave w owns cols w*16..+15.
__global__ __launch_bounds__(512, 6)
void in_edge_kernel(const float* __restrict__ node_x, const unsigned short* __restrict__ nxbf,
                    const float* __restrict__ edge_attr,
                    const int* __restrict__ eidx, const unsigned short* __restrict__ wp,
                    const float* __restrict__ b0p, const float* __restrict__ b1p,
                    const float* __restrict__ b2p, const float* __restrict__ gp,
                    const float* __restrict__ bep,
                    unsigned short* __restrict__ msg, int* __restrict__ head,
                    int* __restrict__ nxt, float* __restrict__ agg,
                    int use_sort, int E) {
  __shared__ unsigned short sBuf[3072 * 8];   // 48KB: tiles x_dst/C0/h2 | x_src/C1 | ea
  __shared__ int sSrc[64], sDst[64];
  __shared__ float sG[128], sB[128];

  const int t = threadIdx.x;
  const int e0 = blockIdx.x * 64;
  const int lane = t & 63, w = t >> 6;
  const int ln = lane & 15, g16 = lane >> 4;
  const int ql = ln * 4 + g16;                 // MFMA read chunk (pre-XOR)
  const int keyw = (w >> 1) & 3;               // C-store XOR key
  // C-store: addr = base + ((w>>1)*4+m)*512 + ri*32 + stoffX
  const int stoffX = g16 * 128 + ((((2 * w) + (ln >> 3)) & 3) ^ keyw) * 8 + (ln & 7);

  // L0 B pipeline: 4-deep register rotation (R7-validated), reused as B2r later
  bf16x8 bx[4], B1r[4];
#pragma unroll
  for (int k = 0; k < 4; ++k)
    bx[k] = *(const bf16x8*)(wp + (size_t)((w * 12 + k) * 64 + lane) * 8);
#pragma unroll
  for (int k = 0; k < 4; ++k)
    B1r[k] = *(const bf16x8*)(wp + 49152 + (size_t)((w * 4 + k) * 64 + lane) * 8);

  if (t < 64) {
    sSrc[t] = (e0 + t < E) ? eidx[e0 + t] : 0;
  } else if (t < 128) {
    int r = t - 64;
    int e = e0 + r;
    int d = (e < E) ? eidx[E + e] : 0;
    sDst[r] = d;
    if (use_sort && e < E) nxt[e] = atomicExch(&head[d], e);   // linked-list build
  } else if (t < 256) {
    sG[t - 128] = gp[t - 128];
  } else if (t < 384) {
    sB[t - 256] = bep[t - 256];
  }
  __syncthreads();

  // ---- stage x tiles: 64B per thread, one pass (4 threads/row per tile) ----
  if (nxbf) {
    int sel = w >> 2;                          // 0: x_dst, 1: x_src
    int row = (w * 16 + (lane >> 2)) & 63;
    int tt = lane & 3;                         // 64B segment = jc 4t..4t+3
    const int* idxp = sel ? sSrc : sDst;
    uint4 v[4] = {{0,0,0,0},{0,0,0,0},{0,0,0,0},{0,0,0,0}};
    if (e0 + row < E) {
      const unsigned short* sp = nxbf + (size_t)idxp[row] * FD + tt * 32;
#pragma unroll
      for (int i = 0; i < 4; ++i) v[i] = *(const uint4*)(sp + i * 8);
    }
    int grp = tt * 4 + (row >> 4);
    int base = sel * 8192 + grp * 512 + (row & 15) * 32;   // q0*8 shorts
#pragma unroll
    for (int i = 0; i < 4; ++i)
      *(uint4*)&sBuf[base + ((i ^ tt) * 8)] = v[i];        // key = (grp>>2)&3 = tt
  } else {
#pragma unroll
    for (int it = 0; it < 2; ++it) {
      int sel = w >> 2;
      int row = (w * 16 + (lane >> 2)) & 63;
      int seg = (lane & 3) + it * 4;           // 16-float segment 0..7
      const int* idxp = sel ? sSrc : sDst;
      f32x4 f[4] = {{0,0,0,0},{0,0,0,0},{0,0,0,0},{0,0,0,0}};
      if (e0 + row < E) {
        const float* sp = node_x + (size_t)idxp[row] * FD + seg * 16;
#pragma unroll
        for (int i = 0; i < 4; ++i) f[i] = *(const f32x4*)(sp + i * 4);
      }
      int jc = seg * 2;                        // two 16B chunks jc, jc+1
      int grp = (jc >> 2) * 4 + (row >> 4);
      int key = (grp >> 2) & 3;
      int tb = sel * 8192 + grp * 512;
      int q0 = (row & 15) * 4 + (jc & 3);
      *(uint4*)&sBuf[tb + ((q0 ^ key) * 8)]       = pack8v(f[0], f[1]);
      *(uint4*)&sBuf[tb + (((q0 + 1) ^ key) * 8)] = pack8v(f[2], f[3]);
    }
  }
  // ---- stage edge_attr: 64B f32 -> 32B bf16 per thread, one pass ----
  {
    int row = t >> 3, seg = t & 7;
    f32x4 f[4] = {{0,0,0,0},{0,0,0,0},{0,0,0,0},{0,0,0,0}};
    if (e0 + row < E) {
      const float* sp = edge_attr + (size_t)(e0 + row) * FD + seg * 16;
#pragma unroll
      for (int i = 0; i < 4; ++i) f[i] = *(const f32x4*)(sp + i * 4);
    }
    int jc = seg * 2;
    int grp = (jc >> 2) * 4 + (row >> 4);
    int key = (grp >> 2) & 3;
    int tb = 16384 + grp * 512;
    int q0 = (row & 15) * 4 + (jc & 3);
    *(uint4*)&sBuf[tb + ((q0 ^ key) * 8)]       = pack8v(f[0], f[1]);
    *(uint4*)&sBuf[tb + (((q0 + 1) ^ key) * 8)] = pack8v(f[2], f[3]);
  }
  __syncthreads();

  const int col = w * 16 + ln;
  const float b0v = b0p[col], b1v = b1p[col], b2v = b2p[col];

  f32x4 acc[4];
#pragma unroll
  for (int m = 0; m < 4; ++m) acc[m] = (f32x4){0.f, 0.f, 0.f, 0.f};

  // ---- layer 0: K=384, 4-deep pipelined B ----
  __builtin_amdgcn_s_setprio(1);
#pragma unroll
  for (int ks = 0; ks < 12; ++ks) {
    bf16x8 bb = bx[ks & 3];
    if (ks + 4 < 12)
      bx[ks & 3] = *(const bf16x8*)(wp + (size_t)((w * 12 + ks + 4) * 64 + lane) * 8);
#pragma unroll
    for (int m = 0; m < 4; ++m) {
      bf16x8 a = *(const bf16x8*)&sBuf[(ks * 4 + m) * 512 + ((ql ^ (ks & 3)) * 8)];
      acc[m] = __builtin_amdgcn_mfma_f32_16x16x32_bf16(a, bb, acc[m], 0, 0, 0);
    }
  }
  __builtin_amdgcn_s_setprio(0);
#pragma unroll
  for (int k = 0; k < 4; ++k)                  // bx -> B2r (hidden under barrier/store)
    bx[k] = *(const bf16x8*)(wp + 65536 + (size_t)((w * 4 + k) * 64 + lane) * 8);
  __syncthreads();                             // all L0 A-reads done

  // C0 -> tile0
#pragma unroll
  for (int m = 0; m < 4; ++m)
#pragma unroll
    for (int ri = 0; ri < 4; ++ri) {
      union { __bf16 h; unsigned short s; } cv;
      cv.h = (__bf16)fmaxf(acc[m][ri] + b0v, 0.f);
      sBuf[((w >> 1) * 4 + m) * 512 + ri * 32 + stoffX] = cv.s;
      acc[m][ri] = 0.f;
    }
  __syncthreads();

  // ---- layer 1 ----
  __builtin_amdgcn_s_setprio(1);
#pragma unroll
  for (int ks = 0; ks < 4; ++ks)
#pragma unroll
    for (int m = 0; m < 4; ++m) {
      bf16x8 a = *(const bf16x8*)&sBuf[(ks * 4 + m) * 512 + ((ql ^ ks) * 8)];
      acc[m] = __builtin_amdgcn_mfma_f32_16x16x32_bf16(a, B1r[ks], acc[m], 0, 0, 0);
    }
  __builtin_amdgcn_s_setprio(0);
  // C1 -> tile1 (x_src dead)
#pragma unroll
  for (int m = 0; m < 4; ++m)
#pragma unroll
    for (int ri = 0; ri < 4; ++ri) {
      union { __bf16 h; unsigned short s; } cv;
      cv.h = (__bf16)fmaxf(acc[m][ri] + b1v, 0.f);
      sBuf[8192 + ((w >> 1) * 4 + m) * 512 + ri * 32 + stoffX] = cv.s;
      acc[m][ri] = 0.f;
    }
  __syncthreads();

  // ---- layer 2 ----
  __builtin_amdgcn_s_setprio(1);
#pragma unroll
  for (int ks = 0; ks < 4; ++ks)
#pragma unroll
    for (int m = 0; m < 4; ++m) {
      bf16x8 a = *(const bf16x8*)&sBuf[8192 + (ks * 4 + m) * 512 + ((ql ^ ks) * 8)];
      acc[m] = __builtin_amdgcn_mfma_f32_16x16x32_bf16(a, bx[ks], acc[m], 0, 0, 0);
    }
  __builtin_amdgcn_s_setprio(0);
  // h2 -> tile0 (C0 dead)
#pragma unroll
  for (int m = 0; m < 4; ++m)
#pragma unroll
    for (int ri = 0; ri < 4; ++ri) {
      union { __bf16 h; unsigned short s; } cv;
      cv.h = (__bf16)(acc[m][ri] + b2v);
      sBuf[((w >> 1) * 4 + m) * 512 + ri * 32 + stoffX] = cv.s;
    }
  __syncthreads();

  // ---- fused LN stats + epilogue, row-wise (8 threads per row) ----
  {
    int row = t >> 3, j = t & 7;
    int grp = (j >> 1) * 4 + (row >> 4);
    int key = (j >> 1) & 3;
    int qa = ((row & 15) * 4 + 2 * (j & 1)) ^ key;
    int qb = ((row & 15) * 4 + 2 * (j & 1) + 1) ^ key;
    int a0 = grp * 512 + qa * 8;
    int a1 = grp * 512 + qb * 8;
    bf16x8 v0 = *(const bf16x8*)&sBuf[a0];
    bf16x8 v1 = *(const bf16x8*)&sBuf[a1];
    float s1 = 0.f, s2 = 0.f;
#pragma unroll
    for (int q = 0; q < 8; ++q) {
      float a = (float)v0[q], b = (float)v1[q];
      s1 += a + b; s2 += a * a + b * b;
    }
#pragma unroll
    for (int m = 1; m < 8; m <<= 1) {
      s1 += __shfl_xor(s1, m, 64);
      s2 += __shfl_xor(s2, m, 64);
    }
    float mean = s1 * (1.f / 128.f);
    float var  = s2 * (1.f / 128.f) - mean * mean;
    float rstd = rsqrtf(fmaxf(var, 0.f) + 1e-5f);

    int e = e0 + row;
    if (e < E) {
      bf16x8 ea0 = *(const bf16x8*)&sBuf[16384 + a0];
      bf16x8 ea1 = *(const bf16x8*)&sBuf[16384 + a1];
      float val[16];
#pragma unroll
      for (int q = 0; q < 8; ++q) {
        val[q]     = ((float)v0[q] - mean) * rstd * sG[j * 16 + q]     + sB[j * 16 + q]     + (float)ea0[q];
        val[8 + q] = ((float)v1[q] - mean) * rstd * sG[j * 16 + 8 + q] + sB[j * 16 + 8 + q] + (float)ea1[q];
      }
      if (use_sort) {
        uint4* dst = (uint4*)(msg + (size_t)e * FD + j * 16);
        dst[0] = pack8(val);
        dst[1] = pack8(val + 8);
      } else {
        float* ap = agg + (size_t)sDst[row] * FD + j * 16;
#pragma unroll
        for (int q = 0; q < 16; ++q) atomicAdd(ap + q, val[q]);
      }
    }
  }
}

// Node kernel: 64 nodes/block (R7 verbatim, un-swizzled frag order).
__global__ __launch_bounds__(512, 8)
void in_node_kernel(const float* __restrict__ node_x, const unsigned short* __restrict__ nxbf,
                    const unsigned short* __restrict__ msg, const int* __restrict__ head,
                    const int* __restrict__ nxt, const float* __restrict__ agg,
                    const unsigned short* __restrict__ wp,
                    const float* __restrict__ b0p, const float* __restrict__ b1p,
                    const float* __restrict__ b2p, const float* __restrict__ gp,
                    const float* __restrict__ bep, float* __restrict__ out,
                    int use_sort, int N) {
  __shared__ unsigned short sBuf[2048 * 8];   // 32KB frag-order buffer
  __shared__ float sG[128], sB[128];

  const int t = threadIdx.x;
  const int r0 = blockIdx.x * 64;
  const int lane = t & 63, w = t >> 6;
  const int ln = lane & 15, g16 = lane >> 4;
  const int col = w * 16 + ln;
  const int rdoff = ln * 32 + g16 * 8;
  const int stoff = (w >> 1) * 2048 + g16 * 128
                  + (((2 * w) + (ln >> 3)) & 3) * 8 + (ln & 7);

  bf16x8 b0[4];
#pragma unroll
  for (int ks = 0; ks < 4; ++ks)
    b0[ks] = *(const bf16x8*)(wp + 81920 + (size_t)((w * 8 + ks) * 64 + lane) * 8);

  if (t < 128)      sG[t] = gp[t];
  else if (t < 256) sB[t - 128] = bep[t - 128];

  if (nxbf) {
#pragma unroll
    for (int it = 0; it < 2; ++it) {
      int f = t + it * 512;
      int row = f >> 4, j = f & 15;
      int r = r0 + row;
      uint4 v = {0, 0, 0, 0};
      if (r < N) v = *(const uint4*)(nxbf + (size_t)r * FD + j * 8);
      int c = (((j >> 2) * 4 + (row >> 4)) * 64 + (row & 15) * 4 + (j & 3)) * 8;
      *(uint4*)&sBuf[c] = v;
    }
  } else {
#pragma unroll
    for (int it = 0; it < 2; ++it) {
      int f = t + it * 512;
      int row = f >> 4, j = f & 15;
      int r = r0 + row;
      f32x4 fa = {0,0,0,0}, fb = {0,0,0,0};
      if (r < N) {
        fa = *(const f32x4*)(node_x + (size_t)r * FD + j * 8);
        fb = *(const f32x4*)(node_x + (size_t)r * FD + j * 8 + 4);
      }
      int c = (((j >> 2) * 4 + (row >> 4)) * 64 + (row & 15) * 4 + (j & 3)) * 8;
      *(uint4*)&sBuf[c] = pack8v(fa, fb);
    }
  }

  {
    int row = t >> 3, j = t & 7;
    int node = r0 + row;
    float a[16];
#pragma unroll
    for (int q = 0; q < 16; ++q) a[q] = 0.f;
    if (node < N) {
      if (use_sort) {
        int e = head[node];
        while (e >= 0) {
          int ne = nxt[e];
          bf16x8 m0 = *(const bf16x8*)(msg + (size_t)e * FD + j * 16);
          bf16x8 m1 = *(const bf16x8*)(msg + (size_t)e * FD + j * 16 + 8);
#pragma unroll
          for (int q = 0; q < 8; ++q) { a[q] += (float)m0[q]; a[8 + q] += (float)m1[q]; }
          e = ne;
        }
      } else {
        const float* ap = agg + (size_t)node * FD + j * 16;
#pragma unroll
        for (int q4 = 0; q4 < 4; ++q4) {
          f32x4 u = *(const f32x4*)(ap + q4 * 4);
#pragma unroll
          for (int q = 0; q < 4; ++q) a[q4 * 4 + q] = u[q];
        }
      }
    }
    int c = 8192 + (((j >> 1) * 4 + (row >> 4)) * 64 + (row & 15) * 4 + 2 * (j & 1)) * 8;
    *(uint4*)&sBuf[c] = pack8(a);
    *(uint4*)&sBuf[c + 8] = pack8(a + 8);
  }
  __syncthreads();

  const float b0v = b0p[col], b1v = b1p[col], b2v = b2p[col];

  f32x4 acc[4];
#pragma unroll
  for (int m = 0; m < 4; ++m) acc[m] = (f32x4){0.f, 0.f, 0.f, 0.f};

#pragma unroll
  for (int ks = 0; ks < 8; ++ks) {
    bf16x8 bb = b0[ks % 4];
    if (ks + 4 < 8)
      b0[ks % 4] = *(const bf16x8*)(wp + 81920 + (size_t)((w * 8 + ks + 4) * 64 + lane) * 8);
#pragma unroll
    for (int m = 0; m < 4; ++m) {
      bf16x8 a = *(const bf16x8*)&sBuf[(ks * 4 + m) * 512 + rdoff];
      acc[m] = __builtin_amdgcn_mfma_f32_16x16x32_bf16(a, bb, acc[m], 0, 0, 0);
    }
  }
  bf16x8 B1r[4];
#pragma unroll
  for (int ks = 0; ks < 4; ++ks)
    B1r[ks] = *(const bf16x8*)(wp + 114688 + (size_t)((w * 4 + ks) * 64 + lane) * 8);

  __syncthreads();
#pragma unroll
  for (int m = 0; m < 4; ++m)
#pragma unroll
    for (int ri = 0; ri < 4; ++ri) {
      union { __bf16 h; unsigned short s; } cv;
      cv.h = (__bf16)fmaxf(acc[m][ri] + b0v, 0.f);
      sBuf[stoff + m * 512 + ri * 32] = cv.s;
      acc[m][ri] = 0.f;
    }
  __syncthreads();

#pragma unroll
  for (int ks = 0; ks < 4; ++ks)
#pragma unroll
    for (int m = 0; m < 4; ++m) {
      bf16x8 a = *(const bf16x8*)&sBuf[(ks * 4 + m) * 512 + rdoff];
      acc[m] = __builtin_amdgcn_mfma_f32_16x16x32_bf16(a, B1r[ks], acc[m], 0, 0, 0);
    }
  bf16x8 B2r[4];
#pragma unroll
  for (int ks = 0; ks < 4; ++ks)
    B2r[ks] = *(const bf16x8*)(wp + 131072 + (size_t)((w * 4 + ks) * 64 + lane) * 8);
#pragma unroll
  for (int m = 0; m < 4; ++m)
#pragma unroll
    for (int ri = 0; ri < 4; ++ri) {
      union { __bf16 h; unsigned short s; } cv;
      cv.h = (__bf16)fmaxf(acc[m][ri] + b1v, 0.f);
      sBuf[8192 + stoff + m * 512 + ri * 32] = cv.s;
      acc[m][ri] = 0.f;
    }
  __syncthreads();

#pragma unroll
  for (int ks = 0; ks < 4; ++ks)
#pragma unroll
    for (int m = 0; m < 4; ++m) {
      bf16x8 a = *(const bf16x8*)&sBuf[8192 + (ks * 4 + m) * 512 + rdoff];
      acc[m] = __builtin_amdgcn_mfma_f32_16x16x32_bf16(a, B2r[ks], acc[m], 0, 0, 0);
    }
#pragma unroll
  for (int m = 0; m < 4; ++m)
#pragma unroll
    for (int ri = 0; ri < 4; ++ri) {
      union { __bf16 h; unsigned short s; } cv;
      cv.h = (__bf16)(acc[m][ri] + b2v);
      sBuf[stoff + m * 512 + ri * 32] = cv.s;
    }
  __syncthreads();

  {
    int row = t >> 3, j = t & 7;
    int a0 = (((j >> 1) * 4 + (row >> 4)) * 64 + (row & 15) * 4 + 2 * (j & 1)) * 8;
    bf16x8 v0 = *(const bf16x8*)&sBuf[a0];
    bf16x8 v1 = *(const bf16x8*)&sBuf[a0 + 8];
    float s1 = 0.f, s2 = 0.f;
#pragma unroll
    for (int q = 0; q < 8; ++q) {
      float a = (float)v0[q], b = (float)v1[q];
      s1 += a + b; s2 += a * a + b * b;
    }
#pragma unroll
    for (int m = 1; m < 8; m <<= 1) {
      s1 += __shfl_xor(s1, m, 64);
      s2 += __shfl_xor(s2, m, 64);
    }
    float mean = s1 * (1.f / 128.f);
    float var  = s2 * (1.f / 128.f) - mean * mean;
    float rstd = rsqrtf(fmaxf(var, 0.f) + 1e-5f);

    int node = r0 + row;
    if (node < N) {
      float o[16];
#pragma unroll
      for (int q = 0; q < 8; ++q) {
        o[q]     = ((float)v0[q] - mean) * rstd * sG[j * 16 + q]     + sB[j * 16 + q];
        o[8 + q] = ((float)v1[q] - mean) * rstd * sG[j * 16 + 8 + q] + sB[j * 16 + 8 + q];
      }
      const float* xr = node_x + (size_t)node * FD + j * 16;
      float* orow = out + (size_t)node * FD + j * 16;
#pragma unroll
      for (int q4 = 0; q4 < 4; ++q4) {
        f32x4 x = *(const f32x4*)(xr + q4 * 4);
        f32x4 wv;
#pragma unroll
        for (int q = 0; q < 4; ++q) wv[q] = o[q4 * 4 + q] + x[q];
        *(f32x4*)(orow + q4 * 4) = wv;
      }
    }
  }
}

extern "C" void kernel_launch(void* const* d_in, const int* in_sizes, int n_in,
                              void* d_out, int out_size, void* d_ws, size_t ws_size,
                              hipStream_t stream) {
  const float* node_x    = (const float*)d_in[0];
  const float* edge_attr = (const float*)d_in[1];
  const int*   eidx      = (const int*)d_in[2];
  const int N = in_sizes[0] / FD;
  const int E = in_sizes[1] / FD;

  char* ws = (char*)d_ws;
  auto aln = [](size_t x) { return (x + 255) & ~(size_t)255; };
  const size_t wpB   = aln(294912);
  const size_t nxbfB = aln((size_t)N * FD * 2);
  const size_t headB = aln((size_t)N * 4);
  const size_t nxtB  = aln((size_t)E * 4);
  const size_t msgB  = (size_t)E * FD * 2;

  unsigned short* wp = (unsigned short*)ws;
  unsigned short* nxbf = nullptr;
  int* head = nullptr; int* nxt = nullptr;
  unsigned short* msg = nullptr; float* agg = nullptr;
  int use_sort = 0;

  if (ws_size >= wpB + nxbfB + headB + nxtB + msgB) {          // full: bf16 table + sort
    use_sort = 1;
    nxbf = (unsigned short*)(ws + wpB);
    head = (int*)(ws + wpB + nxbfB);
    nxt  = (int*)(ws + wpB + nxbfB + headB);
    msg  = (unsigned short*)(ws + wpB + nxbfB + headB + nxtB);
  } else if (ws_size >= wpB + headB + nxtB + msgB) {           // sort, no bf16 table
    use_sort = 1;
    head = (int*)(ws + wpB);
    nxt  = (int*)(ws + wpB + headB);
    msg  = (unsigned short*)(ws + wpB + headB + nxtB);
  } else {                                                     // atomic fallback
    agg = (float*)(ws + wpB);
  }

  if (use_sort) (void)hipMemsetAsync(head, 0xFF, (size_t)N * 4, stream);
  else          (void)hipMemsetAsync(agg, 0, (size_t)N * FD * sizeof(float), stream);

  pack_weights<<<576, 256, 0, stream>>>(
      (const float*)d_in[3], (const float*)d_in[5], (const float*)d_in[7],
      (const float*)d_in[11], (const float*)d_in[13], (const float*)d_in[15], wp);
  if (nxbf) cvt_bf16<<<(N * FD / 8 + 255) / 256, 256, 0, stream>>>(node_x, nxbf, N * FD / 8);
  in_edge_kernel<<<(E + 63) / 64, 512, 0, stream>>>(
      node_x, nxbf, edge_attr, eidx, wp,
      (const float*)d_in[4], (const float*)d_in[6], (const float*)d_in[8],
      (const float*)d_in[9], (const float*)d_in[10],
      msg, head, nxt, agg, use_sort, E);
  in_node_kernel<<<(N + 63) / 64, 512, 0, stream>>>(
      node_x, nxbf, msg, head, nxt, agg, wp,
      (const float*)d_in[12], (const float*)d_in[14], (const float*)d_in[16],
      (const float*)d_in[17], (const float*)d_in[18], (float*)d_out, use_sort, N);
}